// Round 1
// baseline (5495.657 us; speedup 1.0000x reference)
//
#include <hip/hip_runtime.h>
#include <cstdint>
#include <cstddef>

#define HDIM 1024
#define NE 4
#define NL 2
#define NHD 16
#define SEQ 512
#define BATCH 8
#define HFF 2816
#define KEEP 30
#define TOK (BATCH*SEQ)   // 4096
#define MKP 256           // padded keep-rows (240 -> 256)
#define EPSV 1e-5f

typedef __bf16 bf16;
typedef bf16 bf16x8 __attribute__((ext_vector_type(8)));
typedef bf16 bf16x4 __attribute__((ext_vector_type(4)));
typedef float f32x4 __attribute__((ext_vector_type(4)));

// ---------------- concat pose|scene -> x [TOK, HDIM] ----------------
__global__ __launch_bounds__(256) void k_concat(const float* __restrict__ pose,
                                                const float* __restrict__ scene,
                                                float* __restrict__ x) {
  int idx4 = blockIdx.x * 256 + threadIdx.x;     // over TOK*HDIM/4 = 1048576
  int tok = idx4 >> 8;                           // HDIM/4 = 256 vec4 per token
  int c = (idx4 & 255) << 2;
  int b = tok >> 9, s = tok & 511;
  const float* src = (s < 256) ? (pose + ((size_t)(b*256 + s)*HDIM + c))
                               : (scene + ((size_t)(b*256 + (s-256))*HDIM + c));
  *(f32x4*)(x + (size_t)tok*HDIM + c) = *(const f32x4*)src;
}

// ---------------- router (only the 240 kept tokens) ----------------
__global__ __launch_bounds__(64) void k_router(const float* __restrict__ x,
                                               const float* __restrict__ w1, const float* __restrict__ b1,
                                               const float* __restrict__ w2, const float* __restrict__ b2,
                                               float* __restrict__ r) {
  int row = blockIdx.x;                 // b*KEEP + s
  int b = row / KEEP, s = row - b*KEEP;
  int lane = threadIdx.x;
  const float* xr = x + (size_t)(b*SEQ + s)*HDIM;
  float p0=0.f, p1=0.f, p2=0.f, p3=0.f;
  for (int k2 = lane; k2 < HDIM; k2 += 64) {
    float xv = xr[k2];
    const float* wr = w1 + k2*4;
    p0 += xv*wr[0]; p1 += xv*wr[1]; p2 += xv*wr[2]; p3 += xv*wr[3];
  }
  #pragma unroll
  for (int off = 32; off; off >>= 1) {
    p0 += __shfl_xor(p0, off); p1 += __shfl_xor(p1, off);
    p2 += __shfl_xor(p2, off); p3 += __shfl_xor(p3, off);
  }
  if (lane == 0) {
    float gg[4] = {p0 + b1[0], p1 + b1[1], p2 + b1[2], p3 + b1[3]};
    #pragma unroll
    for (int i = 0; i < 4; i++) gg[i] = 0.5f*gg[i]*(1.f + erff(gg[i]*0.70710678f));
    float rr[4], sum = 0.f;
    #pragma unroll
    for (int i = 0; i < 4; i++) {
      float a = b2[i];
      #pragma unroll
      for (int j = 0; j < 4; j++) a += gg[j]*w2[j*4 + i];
      rr[i] = 1.f/(1.f + __expf(-a));
      sum += rr[i];
    }
    float inv = 1.f / fmaxf(sum, 1e-8f);
    #pragma unroll
    for (int i = 0; i < 4; i++) r[row*4 + i] = rr[i]*inv;
  }
}

// ---------------- RMSNorm: fp32 in -> bf16 out ----------------
__global__ __launch_bounds__(256) void k_rmsnorm(const float* __restrict__ in,
                                                 const float* __restrict__ w,
                                                 bf16* __restrict__ out) {
  int row = blockIdx.x, tid = threadIdx.x;
  const float* xr = in + (size_t)row*HDIM;
  f32x4 v = *(const f32x4*)(xr + tid*4);
  float ss = v[0]*v[0] + v[1]*v[1] + v[2]*v[2] + v[3]*v[3];
  #pragma unroll
  for (int off = 32; off; off >>= 1) ss += __shfl_xor(ss, off);
  __shared__ float part[4];
  if ((tid & 63) == 0) part[tid >> 6] = ss;
  __syncthreads();
  float scale = rsqrtf((part[0]+part[1]+part[2]+part[3]) * (1.f/HDIM) + EPSV);
  f32x4 wv = *(const f32x4*)(w + tid*4);
  bf16x4 o;
  #pragma unroll
  for (int i = 0; i < 4; i++) o[i] = (bf16)(v[i]*scale*wv[i]);
  *(bf16x4*)(out + (size_t)row*HDIM + tid*4) = o;
}

// ------------- per-(e,l) weight convert: fp32 [K,N] -> bf16 [N,K] -------------
struct ConvArgs { const float* src[7]; bf16* dst[7]; };
__global__ __launch_bounds__(256) void k_convertT(ConvArgs a) {
  int id = blockIdx.x;   // 12544 tiles total
  int t, base;
  if (id < 4096)      { t = id >> 10; base = t << 10; }
  else if (id < 6912) { t = 4; base = 4096; }
  else if (id < 9728) { t = 5; base = 6912; }
  else                { t = 6; base = 9728; }
  int K = (t == 6) ? HFF : HDIM;
  int N = (t == 4 || t == 5) ? HFF : HDIM;
  int tl = id - base;
  int tilesN = N >> 5;
  int tk = tl / tilesN, tn = tl - tk*tilesN;
  __shared__ float tile[32][33];
  int tx = threadIdx.x & 31, ty = threadIdx.x >> 5;
  const float* src = a.src[t];
  bf16* dst = a.dst[t];
  #pragma unroll
  for (int i = 0; i < 4; i++) {
    int rr = ty + i*8;
    tile[rr][tx] = src[(size_t)(tk*32 + rr)*N + tn*32 + tx];
  }
  __syncthreads();
  #pragma unroll
  for (int i = 0; i < 4; i++) {
    int rr = ty + i*8;
    dst[(size_t)(tn*32 + rr)*K + tk*32 + tx] = (bf16)tile[tx][rr];
  }
}

// ---------------- bf16 MFMA GEMM: C[M,N] = A[M,K] @ Bt[N,K]^T (+bias,+resid,*silu) ----------------
// grid = (N/128, M/128), block = 256 (4 waves, 2x2 of 64x64)
__global__ __launch_bounds__(256) void k_gemm(const bf16* __restrict__ A, const bf16* __restrict__ Bt,
    const float* __restrict__ bias, const float* __restrict__ resid, const bf16* __restrict__ siluSrc,
    float* __restrict__ outF, bf16* __restrict__ outB, int N, int K) {
  __shared__ bf16 As[128][40];
  __shared__ bf16 Bs[128][40];
  int tid = threadIdx.x;
  int wave = tid >> 6, lane = tid & 63;
  int quad = lane >> 4, l16 = lane & 15;
  int wm = (wave >> 1) * 64, wn = (wave & 1) * 64;
  int m0 = blockIdx.y * 128, n0 = blockIdx.x * 128;
  f32x4 zero4 = {0.f, 0.f, 0.f, 0.f};
  f32x4 acc[4][4];
  #pragma unroll
  for (int i = 0; i < 4; i++)
    #pragma unroll
    for (int j = 0; j < 4; j++) acc[i][j] = zero4;
  int srow = tid >> 1, shalf = tid & 1;
  const bf16* Ap = A + (size_t)(m0 + srow)*K + shalf*16;
  const bf16* Bp = Bt + (size_t)(n0 + srow)*K + shalf*16;
  for (int k0 = 0; k0 < K; k0 += 32) {
    bf16x8 a0 = *(const bf16x8*)(Ap + k0);
    bf16x8 a1 = *(const bf16x8*)(Ap + k0 + 8);
    bf16x8 b0 = *(const bf16x8*)(Bp + k0);
    bf16x8 b1 = *(const bf16x8*)(Bp + k0 + 8);
    __syncthreads();
    *(bf16x8*)&As[srow][shalf*16]     = a0;
    *(bf16x8*)&As[srow][shalf*16 + 8] = a1;
    *(bf16x8*)&Bs[srow][shalf*16]     = b0;
    *(bf16x8*)&Bs[srow][shalf*16 + 8] = b1;
    __syncthreads();
    bf16x8 af[4], bq[4];
    #pragma unroll
    for (int i = 0; i < 4; i++) af[i] = *(const bf16x8*)&As[wm + i*16 + l16][quad*8];
    #pragma unroll
    for (int i = 0; i < 4; i++) bq[i] = *(const bf16x8*)&Bs[wn + i*16 + l16][quad*8];
    #pragma unroll
    for (int mi = 0; mi < 4; mi++)
      #pragma unroll
      for (int ni = 0; ni < 4; ni++)
        acc[mi][ni] = __builtin_amdgcn_mfma_f32_16x16x32_bf16(af[mi], bq[ni], acc[mi][ni], 0, 0, 0);
  }
  #pragma unroll
  for (int mi = 0; mi < 4; mi++) {
    #pragma unroll
    for (int ni = 0; ni < 4; ni++) {
      int colg = n0 + wn + ni*16 + l16;
      float bv = bias ? bias[colg] : 0.f;
      #pragma unroll
      for (int rr = 0; rr < 4; rr++) {
        int rowg = m0 + wm + mi*16 + quad*4 + rr;
        size_t off = (size_t)rowg*N + colg;
        float vv = acc[mi][ni][rr] + bv;
        if (resid) vv += resid[off];
        if (siluSrc) { float a = (float)siluSrc[off]; vv *= a / (1.f + __expf(-a)); }
        if (outF) outF[off] = vv;
        else      outB[off] = (bf16)vv;
      }
    }
  }
}

// ---------------- fused non-causal attention (fp32 math, bf16 io) ----------------
// grid = (ceil(qlen/16), NHD, BATCH); q-tile = 16 queries; 512 keys always.
__global__ __launch_bounds__(256) void k_attn(const bf16* __restrict__ q, const bf16* __restrict__ k,
                                              const bf16* __restrict__ v, bf16* __restrict__ o,
                                              int qlen, int orb) {
  __shared__ float Sc[16][516];
  __shared__ float red[16][17];
  int tid = threadIdx.x;
  int qi = tid & 15, ks = tid >> 4;
  int b = blockIdx.z, head = blockIdx.y;
  int q0 = blockIdx.x * 16;
  const bf16* qp = q + (size_t)(b*SEQ + q0 + qi)*HDIM + head*64;
  f32x4 qv[16];
  #pragma unroll
  for (int i = 0; i < 8; i++) {
    bf16x8 t = *(const bf16x8*)(qp + i*8);
    f32x4 lo, hi;
    #pragma unroll
    for (int j = 0; j < 4; j++) { lo[j] = (float)t[j]; hi[j] = (float)t[4+j]; }
    qv[2*i] = lo; qv[2*i+1] = hi;
  }
  const bf16* kbase = k + (size_t)(b*SEQ)*HDIM + head*64;
  for (int jj = 0; jj < 32; jj++) {
    int j = ks*32 + jj;
    const bf16* kp = kbase + (size_t)j*HDIM;
    f32x4 a4 = {0.f, 0.f, 0.f, 0.f};
    #pragma unroll
    for (int i = 0; i < 8; i++) {
      bf16x8 t = *(const bf16x8*)(kp + i*8);
      f32x4 lo, hi;
      #pragma unroll
      for (int jx = 0; jx < 4; jx++) { lo[jx] = (float)t[jx]; hi[jx] = (float)t[4+jx]; }
      a4 += qv[2*i]*lo;
      a4 += qv[2*i+1]*hi;
    }
    Sc[qi][j] = (a4[0]+a4[1]+a4[2]+a4[3]) * 0.125f;
  }
  __syncthreads();
  float m = -1e30f;
  for (int jj = 0; jj < 32; jj++) m = fmaxf(m, Sc[qi][ks*32 + jj]);
  red[qi][ks] = m;
  __syncthreads();
  float rm = red[qi][0];
  #pragma unroll
  for (int i = 1; i < 16; i++) rm = fmaxf(rm, red[qi][i]);
  __syncthreads();
  float sum = 0.f;
  for (int jj = 0; jj < 32; jj++) {
    int j = ks*32 + jj;
    float p = __expf(Sc[qi][j] - rm);
    Sc[qi][j] = p;
    sum += p;
  }
  red[qi][ks] = sum;
  __syncthreads();
  float tot = red[qi][0];
  #pragma unroll
  for (int i = 1; i < 16; i++) tot += red[qi][i];
  float inv = 1.f / tot;
  for (int jj = 0; jj < 32; jj++) Sc[qi][ks*32 + jj] *= inv;
  __syncthreads();
  int ds = ks;
  const bf16* vbase = v + (size_t)(b*SEQ)*HDIM + head*64 + ds*4;
  f32x4 acc = {0.f, 0.f, 0.f, 0.f};
  for (int j4 = 0; j4 < 128; j4++) {
    f32x4 s4 = *(const f32x4*)&Sc[qi][j4*4];
    #pragma unroll
    for (int jx = 0; jx < 4; jx++) {
      bf16x4 v4 = *(const bf16x4*)(vbase + (size_t)(j4*4 + jx)*HDIM);
      float sv = s4[jx];
      acc[0] += sv*(float)v4[0];
      acc[1] += sv*(float)v4[1];
      acc[2] += sv*(float)v4[2];
      acc[3] += sv*(float)v4[3];
    }
  }
  if (q0 + qi < qlen) {
    bf16* op = o + (size_t)(b*orb + q0 + qi)*HDIM + head*64 + ds*4;
    bf16x4 o4;
    #pragma unroll
    for (int i = 0; i < 4; i++) o4[i] = (bf16)acc[i];
    *(bf16x4*)op = o4;
  }
}

// ---------------- gather kept rows of h -> hk (zero-pad 240..255), zero ok pad ----------------
__global__ __launch_bounds__(256) void k_gather(const float* __restrict__ h,
                                                float* __restrict__ hk, bf16* __restrict__ ok) {
  int idx = blockIdx.x*256 + threadIdx.x;    // 256*1024 = 262144
  int row = idx >> 10, col = idx & 1023;
  if (row < BATCH*KEEP) {
    int b = row / KEEP, s = row - b*KEEP;
    hk[idx] = h[(size_t)(b*SEQ + s)*HDIM + col];
  } else {
    hk[idx] = 0.f;
    ok[idx] = (bf16)0.f;
  }
}

// ---------------- combined += hk * r[:,e] ----------------
__global__ __launch_bounds__(256) void k_accum(float* __restrict__ comb, const float* __restrict__ hk,
                                               const float* __restrict__ r, int e, int first) {
  int idx = blockIdx.x*256 + threadIdx.x;    // 240*1024 = 245760
  int row = idx >> 10;
  float vv = hk[idx] * r[row*4 + e];
  comb[idx] = (first ? 0.f : comb[idx]) + vv;
}

// ---------------- final proj (fp32) + LayerNorm ----------------
__global__ __launch_bounds__(256) void k_proj_ln(const float* __restrict__ comb, const float* __restrict__ pw,
    const float* __restrict__ pb, const float* __restrict__ lnw, const float* __restrict__ lnb,
    float* __restrict__ out) {
  int row = blockIdx.x, tid = threadIdx.x;
  __shared__ float xr[HDIM];
  *(f32x4*)&xr[tid*4] = *(const f32x4*)(comb + (size_t)row*HDIM + tid*4);
  __syncthreads();
  f32x4 acc = {0.f, 0.f, 0.f, 0.f};
  #pragma unroll 4
  for (int k2 = 0; k2 < HDIM; k2++) {
    float xv = xr[k2];
    f32x4 w4 = *(const f32x4*)(pw + (size_t)k2*HDIM + tid*4);
    acc += xv * w4;
  }
  f32x4 b4 = *(const f32x4*)(pb + tid*4);
  acc = acc + b4;
  float ps = acc[0]+acc[1]+acc[2]+acc[3];
  #pragma unroll
  for (int off = 32; off; off >>= 1) ps += __shfl_xor(ps, off);
  __shared__ float red1[4], red2[4];
  if ((tid & 63) == 0) red1[tid >> 6] = ps;
  __syncthreads();
  float mu = (red1[0]+red1[1]+red1[2]+red1[3]) * (1.f/HDIM);
  f32x4 d;
  #pragma unroll
  for (int i = 0; i < 4; i++) d[i] = acc[i] - mu;
  float pv = d[0]*d[0]+d[1]*d[1]+d[2]*d[2]+d[3]*d[3];
  #pragma unroll
  for (int off = 32; off; off >>= 1) pv += __shfl_xor(pv, off);
  if ((tid & 63) == 0) red2[tid >> 6] = pv;
  __syncthreads();
  float rs = rsqrtf((red2[0]+red2[1]+red2[2]+red2[3]) * (1.f/HDIM) + EPSV);
  f32x4 lw = *(const f32x4*)(lnw + tid*4);
  f32x4 lb = *(const f32x4*)(lnb + tid*4);
  f32x4 o;
  #pragma unroll
  for (int i = 0; i < 4; i++) o[i] = d[i]*rs*lw[i] + lb[i];
  *(f32x4*)(out + (size_t)row*HDIM + tid*4) = o;
}

extern "C" void kernel_launch(void* const* d_in, const int* in_sizes, int n_in,
                              void* d_out, int out_size, void* d_ws, size_t ws_size,
                              hipStream_t stream) {
  (void)in_sizes; (void)n_in; (void)out_size; (void)ws_size;
  const float* pose = (const float*)d_in[0];
  const float* scene = (const float*)d_in[1];
  const float* rf1w = (const float*)d_in[2];
  const float* rf1b = (const float*)d_in[3];
  const float* rf2w = (const float*)d_in[4];
  const float* rf2b = (const float*)d_in[5];
  const float* anw = (const float*)d_in[6];
  const float* wqw = (const float*)d_in[7];
  const float* wqb = (const float*)d_in[8];
  const float* wkw = (const float*)d_in[9];
  const float* wkb = (const float*)d_in[10];
  const float* wvw = (const float*)d_in[11];
  const float* wvb = (const float*)d_in[12];
  const float* wow = (const float*)d_in[13];
  const float* wob = (const float*)d_in[14];
  const float* fnw = (const float*)d_in[15];
  const float* w1w = (const float*)d_in[16];
  const float* w2w = (const float*)d_in[17];
  const float* w3w = (const float*)d_in[18];
  const float* pw  = (const float*)d_in[19];
  const float* pb  = (const float*)d_in[20];
  const float* lnw = (const float*)d_in[21];
  const float* lnb = (const float*)d_in[22];
  float* out = (float*)d_out;

  char* p = (char*)d_ws;
  auto carve = [&](size_t bytes) { void* r = (void*)p; p += (bytes + 255) & ~(size_t)255; return r; };
  float* x   = (float*)carve((size_t)TOK*HDIM*4);
  float* h   = (float*)carve((size_t)TOK*HDIM*4);
  bf16* xn   = (bf16*)carve((size_t)TOK*HDIM*2);
  bf16* qb_  = (bf16*)carve((size_t)TOK*HDIM*2);
  bf16* kb_  = (bf16*)carve((size_t)TOK*HDIM*2);
  bf16* vb_  = (bf16*)carve((size_t)TOK*HDIM*2);
  bf16* ob_  = (bf16*)carve((size_t)TOK*HDIM*2);
  bf16* a1   = (bf16*)carve((size_t)TOK*HFF*2);
  bf16* g    = (bf16*)carve((size_t)TOK*HFF*2);
  bf16* wqT  = (bf16*)carve((size_t)HDIM*HDIM*2);
  bf16* wkT  = (bf16*)carve((size_t)HDIM*HDIM*2);
  bf16* wvT  = (bf16*)carve((size_t)HDIM*HDIM*2);
  bf16* woT  = (bf16*)carve((size_t)HDIM*HDIM*2);
  bf16* w1T  = (bf16*)carve((size_t)HDIM*HFF*2);
  bf16* w3T  = (bf16*)carve((size_t)HDIM*HFF*2);
  bf16* w2T  = (bf16*)carve((size_t)HFF*HDIM*2);
  float* hk  = (float*)carve((size_t)MKP*HDIM*4);
  bf16* hnk  = (bf16*)carve((size_t)MKP*HDIM*2);
  bf16* okb  = (bf16*)carve((size_t)MKP*HDIM*2);
  float* comb = (float*)carve((size_t)BATCH*KEEP*HDIM*4);
  float* rbuf = (float*)carve((size_t)BATCH*KEEP*4*4);

  k_concat<<<4096, 256, 0, stream>>>(pose, scene, x);
  k_router<<<BATCH*KEEP, 64, 0, stream>>>(x, rf1w, rf1b, rf2w, rf2b, rbuf);

  for (int e = 0; e < NE; e++) {
    for (int l = 0; l < NL; l++) {
      int el = e*NL + l;
      ConvArgs ca;
      ca.src[0] = wqw + (size_t)el*HDIM*HDIM;
      ca.src[1] = wkw + (size_t)el*HDIM*HDIM;
      ca.src[2] = wvw + (size_t)el*HDIM*HDIM;
      ca.src[3] = wow + (size_t)el*HDIM*HDIM;
      ca.src[4] = w1w + (size_t)el*HDIM*HFF;
      ca.src[5] = w3w + (size_t)el*HDIM*HFF;
      ca.src[6] = w2w + (size_t)el*HFF*HDIM;
      ca.dst[0] = wqT; ca.dst[1] = wkT; ca.dst[2] = wvT; ca.dst[3] = woT;
      ca.dst[4] = w1T; ca.dst[5] = w3T; ca.dst[6] = w2T;
      k_convertT<<<12544, 256, 0, stream>>>(ca);

      const float* src_h = (l == 0) ? x : h;
      k_rmsnorm<<<TOK, 256, 0, stream>>>(src_h, anw + (size_t)el*HDIM, xn);
      dim3 gq(8, 32);
      k_gemm<<<gq, 256, 0, stream>>>(xn, wqT, wqb + (size_t)el*HDIM, nullptr, nullptr, nullptr, qb_, HDIM, HDIM);
      k_gemm<<<gq, 256, 0, stream>>>(xn, wkT, wkb + (size_t)el*HDIM, nullptr, nullptr, nullptr, kb_, HDIM, HDIM);
      k_gemm<<<gq, 256, 0, stream>>>(xn, wvT, wvb + (size_t)el*HDIM, nullptr, nullptr, nullptr, vb_, HDIM, HDIM);

      if (l == 0) {
        k_attn<<<dim3(32, NHD, BATCH), 256, 0, stream>>>(qb_, kb_, vb_, ob_, SEQ, SEQ);
        k_gemm<<<dim3(8, 32), 256, 0, stream>>>(ob_, woT, wob + (size_t)el*HDIM, x, nullptr, h, nullptr, HDIM, HDIM);
        k_rmsnorm<<<TOK, 256, 0, stream>>>(h, fnw + (size_t)el*HDIM, xn);
        k_gemm<<<dim3(22, 32), 256, 0, stream>>>(xn, w1T, nullptr, nullptr, nullptr, nullptr, a1, HFF, HDIM);
        k_gemm<<<dim3(22, 32), 256, 0, stream>>>(xn, w3T, nullptr, nullptr, a1, nullptr, g, HFF, HDIM);
        k_gemm<<<dim3(8, 32), 256, 0, stream>>>(g, w2T, nullptr, h, nullptr, h, nullptr, HDIM, HFF);
      } else {
        k_attn<<<dim3(2, NHD, BATCH), 256, 0, stream>>>(qb_, kb_, vb_, okb, KEEP, KEEP);
        k_gather<<<1024, 256, 0, stream>>>(h, hk, okb);
        k_gemm<<<dim3(8, 2), 256, 0, stream>>>(okb, woT, wob + (size_t)el*HDIM, hk, nullptr, hk, nullptr, HDIM, HDIM);
        k_rmsnorm<<<MKP, 256, 0, stream>>>(hk, fnw + (size_t)el*HDIM, hnk);
        k_gemm<<<dim3(22, 2), 256, 0, stream>>>(hnk, w1T, nullptr, nullptr, nullptr, nullptr, a1, HFF, HDIM);
        k_gemm<<<dim3(22, 2), 256, 0, stream>>>(hnk, w3T, nullptr, nullptr, a1, nullptr, g, HFF, HDIM);
        k_gemm<<<dim3(8, 2), 256, 0, stream>>>(g, w2T, nullptr, hk, nullptr, hk, nullptr, HDIM, HFF);
        k_accum<<<960, 256, 0, stream>>>(comb, hk, rbuf, e, (e == 0) ? 1 : 0);
      }
    }
  }
  k_proj_ln<<<240, 256, 0, stream>>>(comb, pw, pb, lnw, lnb, out);
}

// Round 2
// 4337.674 us; speedup vs baseline: 1.2670x; 1.2670x over previous
//
#include <hip/hip_runtime.h>
#include <cstdint>
#include <cstddef>

#define HDIM 1024
#define NE 4
#define NL 2
#define NHD 16
#define SEQ 512
#define BATCH 8
#define HFF 2816
#define KEEP 30
#define TOK (BATCH*SEQ)   // 4096
#define MKP 256           // padded keep-rows (240 -> 256)
#define EPSV 1e-5f

typedef __bf16 bf16;
typedef bf16 bf16x8 __attribute__((ext_vector_type(8)));
typedef bf16 bf16x4 __attribute__((ext_vector_type(4)));
typedef float f32x4 __attribute__((ext_vector_type(4)));

// ---------------- concat pose|scene -> x [TOK, HDIM] ----------------
__global__ __launch_bounds__(256) void k_concat(const float* __restrict__ pose,
                                                const float* __restrict__ scene,
                                                float* __restrict__ x) {
  int idx4 = blockIdx.x * 256 + threadIdx.x;     // over TOK*HDIM/4 = 1048576
  int tok = idx4 >> 8;                           // HDIM/4 = 256 vec4 per token
  int c = (idx4 & 255) << 2;
  int b = tok >> 9, s = tok & 511;
  const float* src = (s < 256) ? (pose + ((size_t)(b*256 + s)*HDIM + c))
                               : (scene + ((size_t)(b*256 + (s-256))*HDIM + c));
  *(f32x4*)(x + (size_t)tok*HDIM + c) = *(const f32x4*)src;
}

// ---------------- router (only the 240 kept tokens) ----------------
__global__ __launch_bounds__(64) void k_router(const float* __restrict__ x,
                                               const float* __restrict__ w1, const float* __restrict__ b1,
                                               const float* __restrict__ w2, const float* __restrict__ b2,
                                               float* __restrict__ r) {
  int row = blockIdx.x;                 // b*KEEP + s
  int b = row / KEEP, s = row - b*KEEP;
  int lane = threadIdx.x;
  const float* xr = x + (size_t)(b*SEQ + s)*HDIM;
  float p0=0.f, p1=0.f, p2=0.f, p3=0.f;
  for (int k2 = lane; k2 < HDIM; k2 += 64) {
    float xv = xr[k2];
    const float* wr = w1 + k2*4;
    p0 += xv*wr[0]; p1 += xv*wr[1]; p2 += xv*wr[2]; p3 += xv*wr[3];
  }
  #pragma unroll
  for (int off = 32; off; off >>= 1) {
    p0 += __shfl_xor(p0, off); p1 += __shfl_xor(p1, off);
    p2 += __shfl_xor(p2, off); p3 += __shfl_xor(p3, off);
  }
  if (lane == 0) {
    float gg[4] = {p0 + b1[0], p1 + b1[1], p2 + b1[2], p3 + b1[3]};
    #pragma unroll
    for (int i = 0; i < 4; i++) gg[i] = 0.5f*gg[i]*(1.f + erff(gg[i]*0.70710678f));
    float rr[4], sum = 0.f;
    #pragma unroll
    for (int i = 0; i < 4; i++) {
      float a = b2[i];
      #pragma unroll
      for (int j = 0; j < 4; j++) a += gg[j]*w2[j*4 + i];
      rr[i] = 1.f/(1.f + __expf(-a));
      sum += rr[i];
    }
    float inv = 1.f / fmaxf(sum, 1e-8f);
    #pragma unroll
    for (int i = 0; i < 4; i++) r[row*4 + i] = rr[i]*inv;
  }
}

// ---------------- RMSNorm: fp32 in -> bf16 out ----------------
__global__ __launch_bounds__(256) void k_rmsnorm(const float* __restrict__ in,
                                                 const float* __restrict__ w,
                                                 bf16* __restrict__ out) {
  int row = blockIdx.x, tid = threadIdx.x;
  const float* xr = in + (size_t)row*HDIM;
  f32x4 v = *(const f32x4*)(xr + tid*4);
  float ss = v[0]*v[0] + v[1]*v[1] + v[2]*v[2] + v[3]*v[3];
  #pragma unroll
  for (int off = 32; off; off >>= 1) ss += __shfl_xor(ss, off);
  __shared__ float part[4];
  if ((tid & 63) == 0) part[tid >> 6] = ss;
  __syncthreads();
  float scale = rsqrtf((part[0]+part[1]+part[2]+part[3]) * (1.f/HDIM) + EPSV);
  f32x4 wv = *(const f32x4*)(w + tid*4);
  bf16x4 o;
  #pragma unroll
  for (int i = 0; i < 4; i++) o[i] = (bf16)(v[i]*scale*wv[i]);
  *(bf16x4*)(out + (size_t)row*HDIM + tid*4) = o;
}

// ------------- per-(e,l) weight convert: fp32 [K,N] -> bf16 [N,K] -------------
struct ConvArgs { const float* src[7]; bf16* dst[7]; };
__global__ __launch_bounds__(256) void k_convertT(ConvArgs a) {
  int id = blockIdx.x;   // 12544 tiles total
  int t, base;
  if (id < 4096)      { t = id >> 10; base = t << 10; }
  else if (id < 6912) { t = 4; base = 4096; }
  else if (id < 9728) { t = 5; base = 6912; }
  else                { t = 6; base = 9728; }
  int K = (t == 6) ? HFF : HDIM;
  int N = (t == 4 || t == 5) ? HFF : HDIM;
  int tl = id - base;
  int tilesN = N >> 5;
  int tk = tl / tilesN, tn = tl - tk*tilesN;
  __shared__ float tile[32][33];
  int tx = threadIdx.x & 31, ty = threadIdx.x >> 5;
  const float* src = a.src[t];
  bf16* dst = a.dst[t];
  #pragma unroll
  for (int i = 0; i < 4; i++) {
    int rr = ty + i*8;
    tile[rr][tx] = src[(size_t)(tk*32 + rr)*N + tn*32 + tx];
  }
  __syncthreads();
  #pragma unroll
  for (int i = 0; i < 4; i++) {
    int rr = ty + i*8;
    dst[(size_t)(tn*32 + rr)*K + tk*32 + tx] = (bf16)tile[tx][rr];
  }
}

// ---------------- bf16 MFMA GEMM: C[M,N] = A[M,K] @ Bt[N,K]^T (+bias,+resid,*silu) ----------------
// grid = (N/128, M/128), block = 256 (4 waves, 2x2 of 64x64)
__global__ __launch_bounds__(256) void k_gemm(const bf16* __restrict__ A, const bf16* __restrict__ Bt,
    const float* __restrict__ bias, const float* __restrict__ resid, const bf16* __restrict__ siluSrc,
    float* __restrict__ outF, bf16* __restrict__ outB, int N, int K) {
  __shared__ bf16 As[128][40];
  __shared__ bf16 Bs[128][40];
  int tid = threadIdx.x;
  int wave = tid >> 6, lane = tid & 63;
  int quad = lane >> 4, l16 = lane & 15;
  int wm = (wave >> 1) * 64, wn = (wave & 1) * 64;
  int m0 = blockIdx.y * 128, n0 = blockIdx.x * 128;
  f32x4 zero4 = {0.f, 0.f, 0.f, 0.f};
  f32x4 acc[4][4];
  #pragma unroll
  for (int i = 0; i < 4; i++)
    #pragma unroll
    for (int j = 0; j < 4; j++) acc[i][j] = zero4;
  int srow = tid >> 1, shalf = tid & 1;
  const bf16* Ap = A + (size_t)(m0 + srow)*K + shalf*16;
  const bf16* Bp = Bt + (size_t)(n0 + srow)*K + shalf*16;
  for (int k0 = 0; k0 < K; k0 += 32) {
    bf16x8 a0 = *(const bf16x8*)(Ap + k0);
    bf16x8 a1 = *(const bf16x8*)(Ap + k0 + 8);
    bf16x8 b0 = *(const bf16x8*)(Bp + k0);
    bf16x8 b1 = *(const bf16x8*)(Bp + k0 + 8);
    __syncthreads();
    *(bf16x8*)&As[srow][shalf*16]     = a0;
    *(bf16x8*)&As[srow][shalf*16 + 8] = a1;
    *(bf16x8*)&Bs[srow][shalf*16]     = b0;
    *(bf16x8*)&Bs[srow][shalf*16 + 8] = b1;
    __syncthreads();
    bf16x8 af[4], bq[4];
    #pragma unroll
    for (int i = 0; i < 4; i++) af[i] = *(const bf16x8*)&As[wm + i*16 + l16][quad*8];
    #pragma unroll
    for (int i = 0; i < 4; i++) bq[i] = *(const bf16x8*)&Bs[wn + i*16 + l16][quad*8];
    #pragma unroll
    for (int mi = 0; mi < 4; mi++)
      #pragma unroll
      for (int ni = 0; ni < 4; ni++)
        acc[mi][ni] = __builtin_amdgcn_mfma_f32_16x16x32_bf16(af[mi], bq[ni], acc[mi][ni], 0, 0, 0);
  }
  #pragma unroll
  for (int mi = 0; mi < 4; mi++) {
    #pragma unroll
    for (int ni = 0; ni < 4; ni++) {
      int colg = n0 + wn + ni*16 + l16;
      float bv = bias ? bias[colg] : 0.f;
      #pragma unroll
      for (int rr = 0; rr < 4; rr++) {
        int rowg = m0 + wm + mi*16 + quad*4 + rr;
        size_t off = (size_t)rowg*N + colg;
        float vv = acc[mi][ni][rr] + bv;
        if (resid) vv += resid[off];
        if (siluSrc) { float a = (float)siluSrc[off]; vv *= a / (1.f + __expf(-a)); }
        if (outF) outF[off] = vv;
        else      outB[off] = (bf16)vv;
      }
    }
  }
}

// ---------------- V transpose: vt[b][h][d][s] = v[b*SEQ+s][h*64+d] ----------------
__global__ __launch_bounds__(256) void k_vtrans(const bf16* __restrict__ v, bf16* __restrict__ vt) {
  __shared__ bf16 t[64][72];
  int b = blockIdx.z, h = blockIdx.y, s0 = blockIdx.x * 64;
  int r = threadIdx.x >> 2, c0 = (threadIdx.x & 3) * 16;
  const bf16* vp = v + (size_t)(b*SEQ + s0 + r)*HDIM + h*64 + c0;
  bf16x8 v0 = *(const bf16x8*)vp;
  bf16x8 v1 = *(const bf16x8*)(vp + 8);
  #pragma unroll
  for (int j = 0; j < 8; j++) { t[r][c0+j] = v0[j]; t[r][c0+8+j] = v1[j]; }
  __syncthreads();
  bf16x8 o0, o1;
  #pragma unroll
  for (int j = 0; j < 8; j++) { o0[j] = t[c0+j][r]; o1[j] = t[c0+8+j][r]; }
  bf16* op = vt + ((size_t)(b*NHD + h)*64 + r)*512 + s0 + c0;
  *(bf16x8*)op = o0;
  *(bf16x8*)(op + 8) = o1;
}

// ---------------- MFMA attention ----------------
// grid (ceil(qlen/64), NH, B), block 256 = 4 waves; wave handles 16 q-rows x 512 keys.
// QK^T: A=Q[q][d], B=K[key][d] straight from global (both contiguous in k=d).
// softmax: per-row via shfl_xor within 16-lane groups (row = quad*4+rr, no LDS).
// PV: A=P from per-wave LDS slice (C-layout -> A-layout round trip), B=Vt[d][key] from global.
__global__ __launch_bounds__(256) void k_attn_mfma(const bf16* __restrict__ q,
    const bf16* __restrict__ k, const bf16* __restrict__ vt,
    bf16* __restrict__ o, int qlen, int orb) {
  __shared__ bf16 Ps[4][16][520];   // pad 8 keeps ds_read_b128 16B-aligned, 2-way row alias
  int tid = threadIdx.x;
  int wave = tid >> 6, lane = tid & 63;
  int quad = lane >> 4, l16 = lane & 15;
  int b = blockIdx.z, head = blockIdx.y;
  int q0 = blockIdx.x * 64 + wave * 16;

  const bf16* qp = q + (size_t)(b*SEQ + q0 + l16)*HDIM + head*64 + quad*8;
  bf16x8 aq0 = *(const bf16x8*)(qp);
  bf16x8 aq1 = *(const bf16x8*)(qp + 32);

  f32x4 z = {0.f, 0.f, 0.f, 0.f};
  f32x4 acc[32];
  #pragma unroll
  for (int ni = 0; ni < 32; ni++) acc[ni] = z;
  const bf16* kb = k + (size_t)(b*SEQ + l16)*HDIM + head*64 + quad*8;
  #pragma unroll 4
  for (int ni = 0; ni < 32; ni++) {
    const bf16* kp = kb + (size_t)(ni*16)*HDIM;
    bf16x8 b0 = *(const bf16x8*)(kp);
    bf16x8 b1 = *(const bf16x8*)(kp + 32);
    acc[ni] = __builtin_amdgcn_mfma_f32_16x16x32_bf16(aq0, b0, acc[ni], 0, 0, 0);
    acc[ni] = __builtin_amdgcn_mfma_f32_16x16x32_bf16(aq1, b1, acc[ni], 0, 0, 0);
  }
  // scale + row max (rows quad*4+rr live in the 16 lanes of this quad)
  float mx[4] = {-3e30f, -3e30f, -3e30f, -3e30f};
  #pragma unroll
  for (int ni = 0; ni < 32; ni++)
    #pragma unroll
    for (int rr = 0; rr < 4; rr++) {
      float s = acc[ni][rr] * 0.125f;
      acc[ni][rr] = s;
      mx[rr] = fmaxf(mx[rr], s);
    }
  #pragma unroll
  for (int off = 1; off <= 8; off <<= 1)
    #pragma unroll
    for (int rr = 0; rr < 4; rr++)
      mx[rr] = fmaxf(mx[rr], __shfl_xor(mx[rr], off));
  float sm[4] = {0.f, 0.f, 0.f, 0.f};
  #pragma unroll
  for (int ni = 0; ni < 32; ni++)
    #pragma unroll
    for (int rr = 0; rr < 4; rr++) {
      float p = __expf(acc[ni][rr] - mx[rr]);
      acc[ni][rr] = p;
      sm[rr] += p;
    }
  #pragma unroll
  for (int off = 1; off <= 8; off <<= 1)
    #pragma unroll
    for (int rr = 0; rr < 4; rr++)
      sm[rr] += __shfl_xor(sm[rr], off);
  // P (unnormalized) -> per-wave LDS slice in A-readable layout
  #pragma unroll
  for (int ni = 0; ni < 32; ni++)
    #pragma unroll
    for (int rr = 0; rr < 4; rr++)
      Ps[wave][quad*4 + rr][ni*16 + l16] = (bf16)acc[ni][rr];
  // PV
  const bf16* vtb = vt + ((size_t)(b*NHD + head)*64 + l16)*512 + quad*8;
  f32x4 accO[4] = {z, z, z, z};
  #pragma unroll 4
  for (int kk = 0; kk < 16; kk++) {
    bf16x8 ap = *(const bf16x8*)&Ps[wave][l16][kk*32 + quad*8];
    #pragma unroll
    for (int ni = 0; ni < 4; ni++) {
      bf16x8 bv = *(const bf16x8*)(vtb + (size_t)(ni*16)*512 + kk*32);
      accO[ni] = __builtin_amdgcn_mfma_f32_16x16x32_bf16(ap, bv, accO[ni], 0, 0, 0);
    }
  }
  float inv[4];
  #pragma unroll
  for (int rr = 0; rr < 4; rr++) inv[rr] = 1.f / sm[rr];
  #pragma unroll
  for (int ni = 0; ni < 4; ni++)
    #pragma unroll
    for (int rr = 0; rr < 4; rr++) {
      int row = q0 + quad*4 + rr;
      if (row < qlen)
        o[(size_t)(b*orb + row)*HDIM + head*64 + ni*16 + l16] = (bf16)(accO[ni][rr] * inv[rr]);
    }
}

// ---------------- gather kept rows of h -> hk (zero-pad 240..255), zero ok pad ----------------
__global__ __launch_bounds__(256) void k_gather(const float* __restrict__ h,
                                                float* __restrict__ hk, bf16* __restrict__ ok) {
  int idx = blockIdx.x*256 + threadIdx.x;    // 256*1024 = 262144
  int row = idx >> 10, col = idx & 1023;
  if (row < BATCH*KEEP) {
    int b = row / KEEP, s = row - b*KEEP;
    hk[idx] = h[(size_t)(b*SEQ + s)*HDIM + col];
  } else {
    hk[idx] = 0.f;
    ok[idx] = (bf16)0.f;
  }
}

// ---------------- combined += hk * r[:,e] ----------------
__global__ __launch_bounds__(256) void k_accum(float* __restrict__ comb, const float* __restrict__ hk,
                                               const float* __restrict__ r, int e, int first) {
  int idx = blockIdx.x*256 + threadIdx.x;    // 240*1024 = 245760
  int row = idx >> 10;
  float vv = hk[idx] * r[row*4 + e];
  comb[idx] = (first ? 0.f : comb[idx]) + vv;
}

// ---------------- final proj (fp32) + LayerNorm ----------------
__global__ __launch_bounds__(256) void k_proj_ln(const float* __restrict__ comb, const float* __restrict__ pw,
    const float* __restrict__ pb, const float* __restrict__ lnw, const float* __restrict__ lnb,
    float* __restrict__ out) {
  int row = blockIdx.x, tid = threadIdx.x;
  __shared__ float xr[HDIM];
  *(f32x4*)&xr[tid*4] = *(const f32x4*)(comb + (size_t)row*HDIM + tid*4);
  __syncthreads();
  f32x4 acc = {0.f, 0.f, 0.f, 0.f};
  #pragma unroll 4
  for (int k2 = 0; k2 < HDIM; k2++) {
    float xv = xr[k2];
    f32x4 w4 = *(const f32x4*)(pw + (size_t)k2*HDIM + tid*4);
    acc += xv * w4;
  }
  f32x4 b4 = *(const f32x4*)(pb + tid*4);
  acc = acc + b4;
  float ps = acc[0]+acc[1]+acc[2]+acc[3];
  #pragma unroll
  for (int off = 32; off; off >>= 1) ps += __shfl_xor(ps, off);
  __shared__ float red1[4], red2[4];
  if ((tid & 63) == 0) red1[tid >> 6] = ps;
  __syncthreads();
  float mu = (red1[0]+red1[1]+red1[2]+red1[3]) * (1.f/HDIM);
  f32x4 d;
  #pragma unroll
  for (int i = 0; i < 4; i++) d[i] = acc[i] - mu;
  float pv = d[0]*d[0]+d[1]*d[1]+d[2]*d[2]+d[3]*d[3];
  #pragma unroll
  for (int off = 32; off; off >>= 1) pv += __shfl_xor(pv, off);
  if ((tid & 63) == 0) red2[tid >> 6] = pv;
  __syncthreads();
  float rs = rsqrtf((red2[0]+red2[1]+red2[2]+red2[3]) * (1.f/HDIM) + EPSV);
  f32x4 lw = *(const f32x4*)(lnw + tid*4);
  f32x4 lb = *(const f32x4*)(lnb + tid*4);
  f32x4 o;
  #pragma unroll
  for (int i = 0; i < 4; i++) o[i] = d[i]*rs*lw[i] + lb[i];
  *(f32x4*)(out + (size_t)row*HDIM + tid*4) = o;
}

extern "C" void kernel_launch(void* const* d_in, const int* in_sizes, int n_in,
                              void* d_out, int out_size, void* d_ws, size_t ws_size,
                              hipStream_t stream) {
  (void)in_sizes; (void)n_in; (void)out_size; (void)ws_size;
  const float* pose = (const float*)d_in[0];
  const float* scene = (const float*)d_in[1];
  const float* rf1w = (const float*)d_in[2];
  const float* rf1b = (const float*)d_in[3];
  const float* rf2w = (const float*)d_in[4];
  const float* rf2b = (const float*)d_in[5];
  const float* anw = (const float*)d_in[6];
  const float* wqw = (const float*)d_in[7];
  const float* wqb = (const float*)d_in[8];
  const float* wkw = (const float*)d_in[9];
  const float* wkb = (const float*)d_in[10];
  const float* wvw = (const float*)d_in[11];
  const float* wvb = (const float*)d_in[12];
  const float* wow = (const float*)d_in[13];
  const float* wob = (const float*)d_in[14];
  const float* fnw = (const float*)d_in[15];
  const float* w1w = (const float*)d_in[16];
  const float* w2w = (const float*)d_in[17];
  const float* w3w = (const float*)d_in[18];
  const float* pw  = (const float*)d_in[19];
  const float* pb  = (const float*)d_in[20];
  const float* lnw = (const float*)d_in[21];
  const float* lnb = (const float*)d_in[22];
  float* out = (float*)d_out;

  char* p = (char*)d_ws;
  auto carve = [&](size_t bytes) { void* r = (void*)p; p += (bytes + 255) & ~(size_t)255; return r; };
  float* x   = (float*)carve((size_t)TOK*HDIM*4);
  float* h   = (float*)carve((size_t)TOK*HDIM*4);
  bf16* xn   = (bf16*)carve((size_t)TOK*HDIM*2);
  bf16* qb_  = (bf16*)carve((size_t)TOK*HDIM*2);
  bf16* kb_  = (bf16*)carve((size_t)TOK*HDIM*2);
  bf16* vb_  = (bf16*)carve((size_t)TOK*HDIM*2);
  bf16* ob_  = (bf16*)carve((size_t)TOK*HDIM*2);
  bf16* vt   = (bf16*)carve((size_t)TOK*HDIM*2);     // vt[b][h][64][512]
  bf16* a1   = (bf16*)carve((size_t)TOK*HFF*2);
  bf16* g    = (bf16*)carve((size_t)TOK*HFF*2);
  bf16* wqT  = (bf16*)carve((size_t)HDIM*HDIM*2);
  bf16* wkT  = (bf16*)carve((size_t)HDIM*HDIM*2);
  bf16* wvT  = (bf16*)carve((size_t)HDIM*HDIM*2);
  bf16* woT  = (bf16*)carve((size_t)HDIM*HDIM*2);
  bf16* w1T  = (bf16*)carve((size_t)HDIM*HFF*2);
  bf16* w3T  = (bf16*)carve((size_t)HDIM*HFF*2);
  bf16* w2T  = (bf16*)carve((size_t)HFF*HDIM*2);
  float* hk  = (float*)carve((size_t)MKP*HDIM*4);
  bf16* hnk  = (bf16*)carve((size_t)MKP*HDIM*2);
  bf16* okb  = (bf16*)carve((size_t)MKP*HDIM*2);
  float* comb = (float*)carve((size_t)BATCH*KEEP*HDIM*4);
  float* rbuf = (float*)carve((size_t)BATCH*KEEP*4*4);

  k_concat<<<4096, 256, 0, stream>>>(pose, scene, x);
  k_router<<<BATCH*KEEP, 64, 0, stream>>>(x, rf1w, rf1b, rf2w, rf2b, rbuf);

  for (int e = 0; e < NE; e++) {
    for (int l = 0; l < NL; l++) {
      int el = e*NL + l;
      ConvArgs ca;
      ca.src[0] = wqw + (size_t)el*HDIM*HDIM;
      ca.src[1] = wkw + (size_t)el*HDIM*HDIM;
      ca.src[2] = wvw + (size_t)el*HDIM*HDIM;
      ca.src[3] = wow + (size_t)el*HDIM*HDIM;
      ca.src[4] = w1w + (size_t)el*HDIM*HFF;
      ca.src[5] = w3w + (size_t)el*HDIM*HFF;
      ca.src[6] = w2w + (size_t)el*HFF*HDIM;
      ca.dst[0] = wqT; ca.dst[1] = wkT; ca.dst[2] = wvT; ca.dst[3] = woT;
      ca.dst[4] = w1T; ca.dst[5] = w3T; ca.dst[6] = w2T;
      k_convertT<<<12544, 256, 0, stream>>>(ca);

      const float* src_h = (l == 0) ? x : h;
      k_rmsnorm<<<TOK, 256, 0, stream>>>(src_h, anw + (size_t)el*HDIM, xn);
      dim3 gq(8, 32);
      k_gemm<<<gq, 256, 0, stream>>>(xn, wqT, wqb + (size_t)el*HDIM, nullptr, nullptr, nullptr, qb_, HDIM, HDIM);
      k_gemm<<<gq, 256, 0, stream>>>(xn, wkT, wkb + (size_t)el*HDIM, nullptr, nullptr, nullptr, kb_, HDIM, HDIM);
      k_gemm<<<gq, 256, 0, stream>>>(xn, wvT, wvb + (size_t)el*HDIM, nullptr, nullptr, nullptr, vb_, HDIM, HDIM);
      k_vtrans<<<dim3(8, NHD, BATCH), 256, 0, stream>>>(vb_, vt);

      if (l == 0) {
        k_attn_mfma<<<dim3(8, NHD, BATCH), 256, 0, stream>>>(qb_, kb_, vt, ob_, SEQ, SEQ);
        k_gemm<<<dim3(8, 32), 256, 0, stream>>>(ob_, woT, wob + (size_t)el*HDIM, x, nullptr, h, nullptr, HDIM, HDIM);
        k_rmsnorm<<<TOK, 256, 0, stream>>>(h, fnw + (size_t)el*HDIM, xn);
        k_gemm<<<dim3(22, 32), 256, 0, stream>>>(xn, w1T, nullptr, nullptr, nullptr, nullptr, a1, HFF, HDIM);
        k_gemm<<<dim3(22, 32), 256, 0, stream>>>(xn, w3T, nullptr, nullptr, a1, nullptr, g, HFF, HDIM);
        k_gemm<<<dim3(8, 32), 256, 0, stream>>>(g, w2T, nullptr, h, nullptr, h, nullptr, HDIM, HFF);
      } else {
        k_attn_mfma<<<dim3(1, NHD, BATCH), 256, 0, stream>>>(qb_, kb_, vt, okb, KEEP, KEEP);
        k_gather<<<1024, 256, 0, stream>>>(h, hk, okb);
        k_gemm<<<dim3(8, 2), 256, 0, stream>>>(okb, woT, wob + (size_t)el*HDIM, hk, nullptr, hk, nullptr, HDIM, HDIM);
        k_rmsnorm<<<MKP, 256, 0, stream>>>(hk, fnw + (size_t)el*HDIM, hnk);
        k_gemm<<<dim3(22, 2), 256, 0, stream>>>(hnk, w1T, nullptr, nullptr, nullptr, nullptr, a1, HFF, HDIM);
        k_gemm<<<dim3(22, 2), 256, 0, stream>>>(hnk, w3T, nullptr, nullptr, a1, nullptr, g, HFF, HDIM);
        k_gemm<<<dim3(8, 2), 256, 0, stream>>>(g, w2T, nullptr, hk, nullptr, hk, nullptr, HDIM, HFF);
        k_accum<<<960, 256, 0, stream>>>(comb, hk, rbuf, e, (e == 0) ? 1 : 0);
      }
    }
  }
  k_proj_ln<<<240, 256, 0, stream>>>(comb, pw, pb, lnw, lnb, out);
}

// Round 3
// 3886.722 us; speedup vs baseline: 1.4140x; 1.1160x over previous
//
#include <hip/hip_runtime.h>
#include <cstdint>
#include <cstddef>

#define HDIM 1024
#define NE 4
#define NL 2
#define NHD 16
#define SEQ 512
#define BATCH 8
#define HFF 2816
#define KEEP 30
#define TOK (BATCH*SEQ)   // 4096
#define MKP 256           // padded keep-rows (240 -> 256)
#define EPSV 1e-5f

typedef __bf16 bf16;
typedef bf16 bf16x8 __attribute__((ext_vector_type(8)));
typedef bf16 bf16x4 __attribute__((ext_vector_type(4)));
typedef float f32x4 __attribute__((ext_vector_type(4)));

// ---------------- concat pose|scene -> x [TOK, HDIM] ----------------
__global__ __launch_bounds__(256) void k_concat(const float* __restrict__ pose,
                                                const float* __restrict__ scene,
                                                float* __restrict__ x) {
  int idx4 = blockIdx.x * 256 + threadIdx.x;     // over TOK*HDIM/4 = 1048576
  int tok = idx4 >> 8;                           // HDIM/4 = 256 vec4 per token
  int c = (idx4 & 255) << 2;
  int b = tok >> 9, s = tok & 511;
  const float* src = (s < 256) ? (pose + ((size_t)(b*256 + s)*HDIM + c))
                               : (scene + ((size_t)(b*256 + (s-256))*HDIM + c));
  *(f32x4*)(x + (size_t)tok*HDIM + c) = *(const f32x4*)src;
}

// ---------------- router (only the 240 kept tokens) ----------------
__global__ __launch_bounds__(64) void k_router(const float* __restrict__ x,
                                               const float* __restrict__ w1, const float* __restrict__ b1,
                                               const float* __restrict__ w2, const float* __restrict__ b2,
                                               float* __restrict__ r) {
  int row = blockIdx.x;                 // b*KEEP + s
  int b = row / KEEP, s = row - b*KEEP;
  int lane = threadIdx.x;
  const float* xr = x + (size_t)(b*SEQ + s)*HDIM;
  float p0=0.f, p1=0.f, p2=0.f, p3=0.f;
  for (int k2 = lane; k2 < HDIM; k2 += 64) {
    float xv = xr[k2];
    const float* wr = w1 + k2*4;
    p0 += xv*wr[0]; p1 += xv*wr[1]; p2 += xv*wr[2]; p3 += xv*wr[3];
  }
  #pragma unroll
  for (int off = 32; off; off >>= 1) {
    p0 += __shfl_xor(p0, off); p1 += __shfl_xor(p1, off);
    p2 += __shfl_xor(p2, off); p3 += __shfl_xor(p3, off);
  }
  if (lane == 0) {
    float gg[4] = {p0 + b1[0], p1 + b1[1], p2 + b1[2], p3 + b1[3]};
    #pragma unroll
    for (int i = 0; i < 4; i++) gg[i] = 0.5f*gg[i]*(1.f + erff(gg[i]*0.70710678f));
    float rr[4], sum = 0.f;
    #pragma unroll
    for (int i = 0; i < 4; i++) {
      float a = b2[i];
      #pragma unroll
      for (int j = 0; j < 4; j++) a += gg[j]*w2[j*4 + i];
      rr[i] = 1.f/(1.f + __expf(-a));
      sum += rr[i];
    }
    float inv = 1.f / fmaxf(sum, 1e-8f);
    #pragma unroll
    for (int i = 0; i < 4; i++) r[row*4 + i] = rr[i]*inv;
  }
}

// ---------------- RMSNorm: fp32 in -> bf16 out ----------------
__global__ __launch_bounds__(256) void k_rmsnorm(const float* __restrict__ in,
                                                 const float* __restrict__ w,
                                                 bf16* __restrict__ out) {
  int row = blockIdx.x, tid = threadIdx.x;
  const float* xr = in + (size_t)row*HDIM;
  f32x4 v = *(const f32x4*)(xr + tid*4);
  float ss = v[0]*v[0] + v[1]*v[1] + v[2]*v[2] + v[3]*v[3];
  #pragma unroll
  for (int off = 32; off; off >>= 1) ss += __shfl_xor(ss, off);
  __shared__ float part[4];
  if ((tid & 63) == 0) part[tid >> 6] = ss;
  __syncthreads();
  float scale = rsqrtf((part[0]+part[1]+part[2]+part[3]) * (1.f/HDIM) + EPSV);
  f32x4 wv = *(const f32x4*)(w + tid*4);
  bf16x4 o;
  #pragma unroll
  for (int i = 0; i < 4; i++) o[i] = (bf16)(v[i]*scale*wv[i]);
  *(bf16x4*)(out + (size_t)row*HDIM + tid*4) = o;
}

// ------------- per-(e,l) weight convert: fp32 [K,N] -> bf16 [N,K] -------------
struct ConvArgs { const float* src[7]; bf16* dst[7]; };
__global__ __launch_bounds__(256) void k_convertT(ConvArgs a) {
  int id = blockIdx.x;   // 12544 tiles total
  int t, base;
  if (id < 4096)      { t = id >> 10; base = t << 10; }
  else if (id < 6912) { t = 4; base = 4096; }
  else if (id < 9728) { t = 5; base = 6912; }
  else                { t = 6; base = 9728; }
  int K = (t == 6) ? HFF : HDIM;
  int N = (t == 4 || t == 5) ? HFF : HDIM;
  int tl = id - base;
  int tilesN = N >> 5;
  int tk = tl / tilesN, tn = tl - tk*tilesN;
  __shared__ float tile[32][33];
  int tx = threadIdx.x & 31, ty = threadIdx.x >> 5;
  const float* src = a.src[t];
  bf16* dst = a.dst[t];
  #pragma unroll
  for (int i = 0; i < 4; i++) {
    int rr = ty + i*8;
    tile[rr][tx] = src[(size_t)(tk*32 + rr)*N + tn*32 + tx];
  }
  __syncthreads();
  #pragma unroll
  for (int i = 0; i < 4; i++) {
    int rr = ty + i*8;
    dst[(size_t)(tn*32 + rr)*K + tk*32 + tx] = (bf16)tile[tx][rr];
  }
}

// ---------------- bf16 MFMA GEMM: C[M,N] = A[M,K] @ Bt[N,K]^T (+bias,+resid,*silu) ----------------
// grid = (N/128, M/128), block = 256 (4 waves, 2x2 of 64x64)
__global__ __launch_bounds__(256) void k_gemm(const bf16* __restrict__ A, const bf16* __restrict__ Bt,
    const float* __restrict__ bias, const float* __restrict__ resid, const bf16* __restrict__ siluSrc,
    float* __restrict__ outF, bf16* __restrict__ outB, int N, int K) {
  __shared__ bf16 As[128][40];
  __shared__ bf16 Bs[128][40];
  int tid = threadIdx.x;
  int wave = tid >> 6, lane = tid & 63;
  int quad = lane >> 4, l16 = lane & 15;
  int wm = (wave >> 1) * 64, wn = (wave & 1) * 64;
  int m0 = blockIdx.y * 128, n0 = blockIdx.x * 128;
  f32x4 zero4 = {0.f, 0.f, 0.f, 0.f};
  f32x4 acc[4][4];
  #pragma unroll
  for (int i = 0; i < 4; i++)
    #pragma unroll
    for (int j = 0; j < 4; j++) acc[i][j] = zero4;
  int srow = tid >> 1, shalf = tid & 1;
  const bf16* Ap = A + (size_t)(m0 + srow)*K + shalf*16;
  const bf16* Bp = Bt + (size_t)(n0 + srow)*K + shalf*16;
  for (int k0 = 0; k0 < K; k0 += 32) {
    bf16x8 a0 = *(const bf16x8*)(Ap + k0);
    bf16x8 a1 = *(const bf16x8*)(Ap + k0 + 8);
    bf16x8 b0 = *(const bf16x8*)(Bp + k0);
    bf16x8 b1 = *(const bf16x8*)(Bp + k0 + 8);
    __syncthreads();
    *(bf16x8*)&As[srow][shalf*16]     = a0;
    *(bf16x8*)&As[srow][shalf*16 + 8] = a1;
    *(bf16x8*)&Bs[srow][shalf*16]     = b0;
    *(bf16x8*)&Bs[srow][shalf*16 + 8] = b1;
    __syncthreads();
    bf16x8 af[4], bq[4];
    #pragma unroll
    for (int i = 0; i < 4; i++) af[i] = *(const bf16x8*)&As[wm + i*16 + l16][quad*8];
    #pragma unroll
    for (int i = 0; i < 4; i++) bq[i] = *(const bf16x8*)&Bs[wn + i*16 + l16][quad*8];
    #pragma unroll
    for (int mi = 0; mi < 4; mi++)
      #pragma unroll
      for (int ni = 0; ni < 4; ni++)
        acc[mi][ni] = __builtin_amdgcn_mfma_f32_16x16x32_bf16(af[mi], bq[ni], acc[mi][ni], 0, 0, 0);
  }
  #pragma unroll
  for (int mi = 0; mi < 4; mi++) {
    #pragma unroll
    for (int ni = 0; ni < 4; ni++) {
      int colg = n0 + wn + ni*16 + l16;
      float bv = bias ? bias[colg] : 0.f;
      #pragma unroll
      for (int rr = 0; rr < 4; rr++) {
        int rowg = m0 + wm + mi*16 + quad*4 + rr;
        size_t off = (size_t)rowg*N + colg;
        float vv = acc[mi][ni][rr] + bv;
        if (resid) vv += resid[off];
        if (siluSrc) { float a = (float)siluSrc[off]; vv *= a / (1.f + __expf(-a)); }
        if (outF) outF[off] = vv;
        else      outB[off] = (bf16)vv;
      }
    }
  }
}

// ---------------- V transpose: vt[b][h][d][s] = v[b*SEQ+s][h*64+d] ----------------
__global__ __launch_bounds__(256) void k_vtrans(const bf16* __restrict__ v, bf16* __restrict__ vt) {
  __shared__ bf16 t[64][72];
  int b = blockIdx.z, h = blockIdx.y, s0 = blockIdx.x * 64;
  int r = threadIdx.x >> 2, c0 = (threadIdx.x & 3) * 16;
  const bf16* vp = v + (size_t)(b*SEQ + s0 + r)*HDIM + h*64 + c0;
  bf16x8 v0 = *(const bf16x8*)vp;
  bf16x8 v1 = *(const bf16x8*)(vp + 8);
  #pragma unroll
  for (int j = 0; j < 8; j++) { t[r][c0+j] = v0[j]; t[r][c0+8+j] = v1[j]; }
  __syncthreads();
  bf16x8 o0, o1;
  #pragma unroll
  for (int j = 0; j < 8; j++) { o0[j] = t[c0+j][r]; o1[j] = t[c0+8+j][r]; }
  bf16* op = vt + ((size_t)(b*NHD + h)*64 + r)*512 + s0 + c0;
  *(bf16x8*)op = o0;
  *(bf16x8*)(op + 8) = o1;
}

// ---------------- MFMA attention ----------------
// grid (ceil(qlen/64), NH, B), block 256 = 4 waves; wave handles 16 q-rows x 512 keys.
// ALL loops touching acc[32] are FULLY unrolled — partial unroll demotes the
// 128-VGPR accumulator array to scratch (R1: 765 MB HBM spill traffic/dispatch).
__global__ __launch_bounds__(256, 1) void k_attn_mfma(const bf16* __restrict__ q,
    const bf16* __restrict__ k, const bf16* __restrict__ vt,
    bf16* __restrict__ o, int qlen, int orb) {
  __shared__ bf16 Ps[4][16][520];   // pad 8 keeps ds_read_b128 16B-aligned, 2-way row alias
  int tid = threadIdx.x;
  int wave = tid >> 6, lane = tid & 63;
  int quad = lane >> 4, l16 = lane & 15;
  int b = blockIdx.z, head = blockIdx.y;
  int q0 = blockIdx.x * 64 + wave * 16;

  const bf16* qp = q + (size_t)(b*SEQ + q0 + l16)*HDIM + head*64 + quad*8;
  bf16x8 aq0 = *(const bf16x8*)(qp);
  bf16x8 aq1 = *(const bf16x8*)(qp + 32);

  f32x4 z = {0.f, 0.f, 0.f, 0.f};
  f32x4 acc[32];
  #pragma unroll
  for (int ni = 0; ni < 32; ni++) acc[ni] = z;
  const bf16* kb = k + (size_t)(b*SEQ + l16)*HDIM + head*64 + quad*8;
  #pragma unroll
  for (int ni = 0; ni < 32; ni++) {
    const bf16* kp = kb + (size_t)(ni*16)*HDIM;
    bf16x8 b0 = *(const bf16x8*)(kp);
    bf16x8 b1 = *(const bf16x8*)(kp + 32);
    acc[ni] = __builtin_amdgcn_mfma_f32_16x16x32_bf16(aq0, b0, acc[ni], 0, 0, 0);
    acc[ni] = __builtin_amdgcn_mfma_f32_16x16x32_bf16(aq1, b1, acc[ni], 0, 0, 0);
  }
  // scale + row max (rows quad*4+rr live in the 16 lanes of this quad)
  float mx[4] = {-3e30f, -3e30f, -3e30f, -3e30f};
  #pragma unroll
  for (int ni = 0; ni < 32; ni++)
    #pragma unroll
    for (int rr = 0; rr < 4; rr++) {
      float s = acc[ni][rr] * 0.125f;
      acc[ni][rr] = s;
      mx[rr] = fmaxf(mx[rr], s);
    }
  #pragma unroll
  for (int off = 1; off <= 8; off <<= 1)
    #pragma unroll
    for (int rr = 0; rr < 4; rr++)
      mx[rr] = fmaxf(mx[rr], __shfl_xor(mx[rr], off));
  float sm[4] = {0.f, 0.f, 0.f, 0.f};
  #pragma unroll
  for (int ni = 0; ni < 32; ni++)
    #pragma unroll
    for (int rr = 0; rr < 4; rr++) {
      float p = __expf(acc[ni][rr] - mx[rr]);
      acc[ni][rr] = p;
      sm[rr] += p;
    }
  #pragma unroll
  for (int off = 1; off <= 8; off <<= 1)
    #pragma unroll
    for (int rr = 0; rr < 4; rr++)
      sm[rr] += __shfl_xor(sm[rr], off);
  // P (unnormalized) -> per-wave LDS slice in A-readable layout
  #pragma unroll
  for (int ni = 0; ni < 32; ni++)
    #pragma unroll
    for (int rr = 0; rr < 4; rr++)
      Ps[wave][quad*4 + rr][ni*16 + l16] = (bf16)acc[ni][rr];
  // PV
  const bf16* vtb = vt + ((size_t)(b*NHD + head)*64 + l16)*512 + quad*8;
  f32x4 accO[4] = {z, z, z, z};
  #pragma unroll 4
  for (int kk = 0; kk < 16; kk++) {
    bf16x8 ap = *(const bf16x8*)&Ps[wave][l16][kk*32 + quad*8];
    #pragma unroll
    for (int ni = 0; ni < 4; ni++) {
      bf16x8 bv = *(const bf16x8*)(vtb + (size_t)(ni*16)*512 + kk*32);
      accO[ni] = __builtin_amdgcn_mfma_f32_16x16x32_bf16(ap, bv, accO[ni], 0, 0, 0);
    }
  }
  float inv[4];
  #pragma unroll
  for (int rr = 0; rr < 4; rr++) inv[rr] = 1.f / sm[rr];
  #pragma unroll
  for (int ni = 0; ni < 4; ni++)
    #pragma unroll
    for (int rr = 0; rr < 4; rr++) {
      int row = q0 + quad*4 + rr;
      if (row < qlen)
        o[(size_t)(b*orb + row)*HDIM + head*64 + ni*16 + l16] = (bf16)(accO[ni][rr] * inv[rr]);
    }
}

// ---------------- gather kept rows of h -> hk (zero-pad 240..255), zero ok pad ----------------
__global__ __launch_bounds__(256) void k_gather(const float* __restrict__ h,
                                                float* __restrict__ hk, bf16* __restrict__ ok) {
  int idx = blockIdx.x*256 + threadIdx.x;    // 256*1024 = 262144
  int row = idx >> 10, col = idx & 1023;
  if (row < BATCH*KEEP) {
    int b = row / KEEP, s = row - b*KEEP;
    hk[idx] = h[(size_t)(b*SEQ + s)*HDIM + col];
  } else {
    hk[idx] = 0.f;
    ok[idx] = (bf16)0.f;
  }
}

// ---------------- combined += hk * r[:,e] ----------------
__global__ __launch_bounds__(256) void k_accum(float* __restrict__ comb, const float* __restrict__ hk,
                                               const float* __restrict__ r, int e, int first) {
  int idx = blockIdx.x*256 + threadIdx.x;    // 240*1024 = 245760
  int row = idx >> 10;
  float vv = hk[idx] * r[row*4 + e];
  comb[idx] = (first ? 0.f : comb[idx]) + vv;
}

// ---------------- final proj (fp32) + LayerNorm ----------------
__global__ __launch_bounds__(256) void k_proj_ln(const float* __restrict__ comb, const float* __restrict__ pw,
    const float* __restrict__ pb, const float* __restrict__ lnw, const float* __restrict__ lnb,
    float* __restrict__ out) {
  int row = blockIdx.x, tid = threadIdx.x;
  __shared__ float xr[HDIM];
  *(f32x4*)&xr[tid*4] = *(const f32x4*)(comb + (size_t)row*HDIM + tid*4);
  __syncthreads();
  f32x4 acc = {0.f, 0.f, 0.f, 0.f};
  #pragma unroll 4
  for (int k2 = 0; k2 < HDIM; k2++) {
    float xv = xr[k2];
    f32x4 w4 = *(const f32x4*)(pw + (size_t)k2*HDIM + tid*4);
    acc += xv * w4;
  }
  f32x4 b4 = *(const f32x4*)(pb + tid*4);
  acc = acc + b4;
  float ps = acc[0]+acc[1]+acc[2]+acc[3];
  #pragma unroll
  for (int off = 32; off; off >>= 1) ps += __shfl_xor(ps, off);
  __shared__ float red1[4], red2[4];
  if ((tid & 63) == 0) red1[tid >> 6] = ps;
  __syncthreads();
  float mu = (red1[0]+red1[1]+red1[2]+red1[3]) * (1.f/HDIM);
  f32x4 d;
  #pragma unroll
  for (int i = 0; i < 4; i++) d[i] = acc[i] - mu;
  float pv = d[0]*d[0]+d[1]*d[1]+d[2]*d[2]+d[3]*d[3];
  #pragma unroll
  for (int off = 32; off; off >>= 1) pv += __shfl_xor(pv, off);
  if ((tid & 63) == 0) red2[tid >> 6] = pv;
  __syncthreads();
  float rs = rsqrtf((red2[0]+red2[1]+red2[2]+red2[3]) * (1.f/HDIM) + EPSV);
  f32x4 lw = *(const f32x4*)(lnw + tid*4);
  f32x4 lb = *(const f32x4*)(lnb + tid*4);
  f32x4 o;
  #pragma unroll
  for (int i = 0; i < 4; i++) o[i] = d[i]*rs*lw[i] + lb[i];
  *(f32x4*)(out + (size_t)row*HDIM + tid*4) = o;
}

extern "C" void kernel_launch(void* const* d_in, const int* in_sizes, int n_in,
                              void* d_out, int out_size, void* d_ws, size_t ws_size,
                              hipStream_t stream) {
  (void)in_sizes; (void)n_in; (void)out_size; (void)ws_size;
  const float* pose = (const float*)d_in[0];
  const float* scene = (const float*)d_in[1];
  const float* rf1w = (const float*)d_in[2];
  const float* rf1b = (const float*)d_in[3];
  const float* rf2w = (const float*)d_in[4];
  const float* rf2b = (const float*)d_in[5];
  const float* anw = (const float*)d_in[6];
  const float* wqw = (const float*)d_in[7];
  const float* wqb = (const float*)d_in[8];
  const float* wkw = (const float*)d_in[9];
  const float* wkb = (const float*)d_in[10];
  const float* wvw = (const float*)d_in[11];
  const float* wvb = (const float*)d_in[12];
  const float* wow = (const float*)d_in[13];
  const float* wob = (const float*)d_in[14];
  const float* fnw = (const float*)d_in[15];
  const float* w1w = (const float*)d_in[16];
  const float* w2w = (const float*)d_in[17];
  const float* w3w = (const float*)d_in[18];
  const float* pw  = (const float*)d_in[19];
  const float* pb  = (const float*)d_in[20];
  const float* lnw = (const float*)d_in[21];
  const float* lnb = (const float*)d_in[22];
  float* out = (float*)d_out;

  char* p = (char*)d_ws;
  auto carve = [&](size_t bytes) { void* r = (void*)p; p += (bytes + 255) & ~(size_t)255; return r; };
  float* x   = (float*)carve((size_t)TOK*HDIM*4);
  float* h   = (float*)carve((size_t)TOK*HDIM*4);
  bf16* xn   = (bf16*)carve((size_t)TOK*HDIM*2);
  bf16* qb_  = (bf16*)carve((size_t)TOK*HDIM*2);
  bf16* kb_  = (bf16*)carve((size_t)TOK*HDIM*2);
  bf16* vb_  = (bf16*)carve((size_t)TOK*HDIM*2);
  bf16* ob_  = (bf16*)carve((size_t)TOK*HDIM*2);
  bf16* vt   = (bf16*)carve((size_t)TOK*HDIM*2);     // vt[b][h][64][512]
  bf16* a1   = (bf16*)carve((size_t)TOK*HFF*2);
  bf16* g    = (bf16*)carve((size_t)TOK*HFF*2);
  bf16* wqT  = (bf16*)carve((size_t)HDIM*HDIM*2);
  bf16* wkT  = (bf16*)carve((size_t)HDIM*HDIM*2);
  bf16* wvT  = (bf16*)carve((size_t)HDIM*HDIM*2);
  bf16* woT  = (bf16*)carve((size_t)HDIM*HDIM*2);
  bf16* w1T  = (bf16*)carve((size_t)HDIM*HFF*2);
  bf16* w3T  = (bf16*)carve((size_t)HDIM*HFF*2);
  bf16* w2T  = (bf16*)carve((size_t)HFF*HDIM*2);
  float* hk  = (float*)carve((size_t)MKP*HDIM*4);
  bf16* hnk  = (bf16*)carve((size_t)MKP*HDIM*2);
  bf16* okb  = (bf16*)carve((size_t)MKP*HDIM*2);
  float* comb = (float*)carve((size_t)BATCH*KEEP*HDIM*4);
  float* rbuf = (float*)carve((size_t)BATCH*KEEP*4*4);

  k_concat<<<4096, 256, 0, stream>>>(pose, scene, x);
  k_router<<<BATCH*KEEP, 64, 0, stream>>>(x, rf1w, rf1b, rf2w, rf2b, rbuf);

  for (int e = 0; e < NE; e++) {
    for (int l = 0; l < NL; l++) {
      int el = e*NL + l;
      ConvArgs ca;
      ca.src[0] = wqw + (size_t)el*HDIM*HDIM;
      ca.src[1] = wkw + (size_t)el*HDIM*HDIM;
      ca.src[2] = wvw + (size_t)el*HDIM*HDIM;
      ca.src[3] = wow + (size_t)el*HDIM*HDIM;
      ca.src[4] = w1w + (size_t)el*HDIM*HFF;
      ca.src[5] = w3w + (size_t)el*HDIM*HFF;
      ca.src[6] = w2w + (size_t)el*HFF*HDIM;
      ca.dst[0] = wqT; ca.dst[1] = wkT; ca.dst[2] = wvT; ca.dst[3] = woT;
      ca.dst[4] = w1T; ca.dst[5] = w3T; ca.dst[6] = w2T;
      k_convertT<<<12544, 256, 0, stream>>>(ca);

      const float* src_h = (l == 0) ? x : h;
      k_rmsnorm<<<TOK, 256, 0, stream>>>(src_h, anw + (size_t)el*HDIM, xn);
      dim3 gq(8, 32);
      k_gemm<<<gq, 256, 0, stream>>>(xn, wqT, wqb + (size_t)el*HDIM, nullptr, nullptr, nullptr, qb_, HDIM, HDIM);
      k_gemm<<<gq, 256, 0, stream>>>(xn, wkT, wkb + (size_t)el*HDIM, nullptr, nullptr, nullptr, kb_, HDIM, HDIM);
      k_gemm<<<gq, 256, 0, stream>>>(xn, wvT, wvb + (size_t)el*HDIM, nullptr, nullptr, nullptr, vb_, HDIM, HDIM);
      k_vtrans<<<dim3(8, NHD, BATCH), 256, 0, stream>>>(vb_, vt);

      if (l == 0) {
        k_attn_mfma<<<dim3(8, NHD, BATCH), 256, 0, stream>>>(qb_, kb_, vt, ob_, SEQ, SEQ);
        k_gemm<<<dim3(8, 32), 256, 0, stream>>>(ob_, woT, wob + (size_t)el*HDIM, x, nullptr, h, nullptr, HDIM, HDIM);
        k_rmsnorm<<<TOK, 256, 0, stream>>>(h, fnw + (size_t)el*HDIM, xn);
        k_gemm<<<dim3(22, 32), 256, 0, stream>>>(xn, w1T, nullptr, nullptr, nullptr, nullptr, a1, HFF, HDIM);
        k_gemm<<<dim3(22, 32), 256, 0, stream>>>(xn, w3T, nullptr, nullptr, a1, nullptr, g, HFF, HDIM);
        k_gemm<<<dim3(8, 32), 256, 0, stream>>>(g, w2T, nullptr, h, nullptr, h, nullptr, HDIM, HFF);
      } else {
        k_attn_mfma<<<dim3(1, NHD, BATCH), 256, 0, stream>>>(qb_, kb_, vt, okb, KEEP, KEEP);
        k_gather<<<1024, 256, 0, stream>>>(h, hk, okb);
        k_gemm<<<dim3(8, 2), 256, 0, stream>>>(okb, woT, wob + (size_t)el*HDIM, hk, nullptr, hk, nullptr, HDIM, HDIM);
        k_rmsnorm<<<MKP, 256, 0, stream>>>(hk, fnw + (size_t)el*HDIM, hnk);
        k_gemm<<<dim3(22, 2), 256, 0, stream>>>(hnk, w1T, nullptr, nullptr, nullptr, nullptr, a1, HFF, HDIM);
        k_gemm<<<dim3(22, 2), 256, 0, stream>>>(hnk, w3T, nullptr, nullptr, a1, nullptr, g, HFF, HDIM);
        k_gemm<<<dim3(8, 2), 256, 0, stream>>>(g, w2T, nullptr, hk, nullptr, hk, nullptr, HDIM, HFF);
        k_accum<<<960, 256, 0, stream>>>(comb, hk, rbuf, e, (e == 0) ? 1 : 0);
      }
    }
  }
  k_proj_ln<<<240, 256, 0, stream>>>(comb, pw, pb, lnw, lnb, out);
}